// Round 1
// baseline (395.099 us; speedup 1.0000x reference)
//
#include <hip/hip_runtime.h>

#define Bn 256
#define Sn 4096
#define Fn 64
#define TCOST 0.0003f
#define INIT_CAP 500.0f

// Output layout (floats):
//   equity      : [B, S+1]        offset 0
//   positions   : [B, S+1, 3]     offset B*(S+1)
//   predictions : [B, S]          offset B*(S+1)*4
//   position_sz : [B]             offset B*(S+1)*4 + B*S
#define EQ_OFF   0
#define POS_OFF  (Bn * (Sn + 1))
#define PRED_OFF (Bn * (Sn + 1) * 4)
#define PSZ_OFF  (PRED_OFF + Bn * Sn)

// Kernel A: per-(b,s) prediction + gumbel-softmax probs + staging of ret_part.
__global__ __launch_bounds__(256) void trishot_fwd(
    const float* __restrict__ feat,     // [B, S, F]
    const float* __restrict__ w,        // [F]
    const float* __restrict__ p_lt, const float* __restrict__ p_st,
    const float* __restrict__ p_bps, const float* __restrict__ p_cs,
    const float* __restrict__ p_vi, const float* __restrict__ p_vct,
    const float* __restrict__ p_vst,
    const float* __restrict__ gumbel,   // [S, B, 3]
    float* __restrict__ out)
{
    int r = blockIdx.x * 256 + threadIdx.x;   // r in [0, B*S)
    int b = r >> 12;                          // S = 4096 = 2^12
    int s = r & (Sn - 1);

    const float LT = *p_lt, ST = *p_st, BPS = *p_bps, CS = *p_cs,
                VI = *p_vi, VCT = *p_vct, VST = *p_vst;

    const float4* f4 = (const float4*)(feat + (size_t)r * Fn);
    const float4* w4 = (const float4*)w;   // uniform -> scalar loads

    float4 f0 = f4[0];
    float a0 = 0.f, a1 = 0.f, a2 = 0.f, a3 = 0.f;
#pragma unroll
    for (int k = 0; k < 16; k++) {
        float4 fv = f4[k];
        float4 wv = w4[k];
        a0 = fmaf(fv.x, wv.x, a0);
        a1 = fmaf(fv.y, wv.y, a1);
        a2 = fmaf(fv.z, wv.z, a2);
        a3 = fmaf(fv.w, wv.w, a3);
    }
    float x = (a0 + a1) + (a2 + a3);
    float p = 1.0f / (1.0f + __expf(-x));

    float mom = f0.x, vix = f0.y, dvix = f0.z, mret = f0.w;

    float ss = fabsf(p - 0.5f) * 2.0f;
    bool collapse = (dvix < -VCT) && (vix < 30.0f);
    bool spike    = (dvix >  VST) && (vix > 20.0f);
    float psz = fminf(fmaxf(BPS + CS * ss, 0.2f), 1.0f);
    if (collapse || spike) psz *= (1.0f + VI);

    bool lp = ((p >= LT) && (mom > 0.0f)) || collapse;
    bool sp = ((p <= ST) && (mom < 0.0f)) || spike;
    float l0 = lp ? 1.0f : -10.0f;
    float l1 = sp ? 1.0f : -10.0f;
    float l2 = (!lp && !sp) ? 1.0f : -10.0f;

    const float* g = gumbel + ((size_t)s * Bn + b) * 3;
    float g0 = g[0], g1 = g[1], g2 = g[2];
    float z0 = l0 + g0, z1 = l1 + g1, z2 = l2 + g2;
    float zm = fmaxf(z0, fmaxf(z1, z2));
    float e0 = __expf(z0 - zm), e1 = __expf(z1 - zm), e2 = __expf(z2 - zm);
    float inv = 1.0f / (e0 + e1 + e2);
    float q0 = e0 * inv, q1 = e1 * inv, q2 = e2 * inv;

    // predictions [B,S]
    out[PRED_OFF + r] = p;

    // positions [B, S+1, 3] at row s+1
    size_t prow = ((size_t)b * (Sn + 1) + s + 1) * 3;
    float* pos = out + POS_OFF;
    pos[prow + 0] = q0;
    pos[prow + 1] = q1;
    pos[prow + 2] = q2;

    // stage ret_part into equity cell [b][s+1] (kernel B overwrites with eq)
    out[EQ_OFF + (size_t)b * (Sn + 1) + s + 1] = psz * (q0 - q1) * mret;

    if (s == 0) {
        size_t p0row = (size_t)b * (Sn + 1) * 3;
        pos[p0row + 0] = 0.0f;
        pos[p0row + 1] = 0.0f;
        pos[p0row + 2] = 1.0f;
    }
    if (s == Sn - 1) {
        out[PSZ_OFF + b] = psz;   // last-step position size
    }
}

// Kernel B: one block per batch element; parallel prefix-product for equity.
#define CH 16   // timesteps per thread (256 threads * 16 = 4096)
__global__ __launch_bounds__(256) void trishot_scan(float* __restrict__ out)
{
    int b = blockIdx.x;
    int j = threadIdx.x;

    float* eq = out + EQ_OFF + (size_t)b * (Sn + 1);
    const float* pos = out + POS_OFF + (size_t)b * (Sn + 1) * 3;

    int t0 = j * CH;
    float prev0 = pos[(size_t)t0 * 3 + 0];
    float prev1 = pos[(size_t)t0 * 3 + 1];
    float prev2 = pos[(size_t)t0 * 3 + 2];

    float f[CH];
    float lprod = 1.0f;
#pragma unroll
    for (int i = 0; i < CH; i++) {
        size_t ci = (size_t)(t0 + i + 1) * 3;
        float c0 = pos[ci + 0], c1 = pos[ci + 1], c2 = pos[ci + 2];
        float pc = fabsf(c0 - prev0) + fabsf(c1 - prev1) + fabsf(c2 - prev2);
        float rp = eq[t0 + i + 1];   // staged ret_part
        float fac = 1.0f + rp - pc * TCOST;
        f[i] = fac;
        lprod *= fac;
        prev0 = c0; prev1 = c1; prev2 = c2;
    }

    __shared__ float sc[256];
    sc[j] = lprod;
    __syncthreads();
    // Hillis-Steele inclusive scan (product)
#pragma unroll
    for (int off = 1; off < 256; off <<= 1) {
        float mine = sc[j];
        float other = (j >= off) ? sc[j - off] : 1.0f;
        __syncthreads();
        sc[j] = mine * other;
        __syncthreads();
    }

    float eqv = INIT_CAP * ((j > 0) ? sc[j - 1] : 1.0f);
#pragma unroll
    for (int i = 0; i < CH; i++) {
        eqv *= f[i];
        eq[t0 + i + 1] = eqv;
    }
    if (j == 0) eq[0] = INIT_CAP;
}

extern "C" void kernel_launch(void* const* d_in, const int* in_sizes, int n_in,
                              void* d_out, int out_size, void* d_ws, size_t ws_size,
                              hipStream_t stream) {
    const float* feat   = (const float*)d_in[0];
    const float* w      = (const float*)d_in[1];
    const float* lt     = (const float*)d_in[2];
    const float* st     = (const float*)d_in[3];
    const float* bps    = (const float*)d_in[4];
    const float* cs     = (const float*)d_in[5];
    const float* vi     = (const float*)d_in[6];
    const float* vct    = (const float*)d_in[7];
    const float* vst    = (const float*)d_in[8];
    const float* gumbel = (const float*)d_in[9];
    float* out = (float*)d_out;

    trishot_fwd<<<(Bn * Sn) / 256, 256, 0, stream>>>(
        feat, w, lt, st, bps, cs, vi, vct, vst, gumbel, out);
    trishot_scan<<<Bn, 256, 0, stream>>>(out);
}